// Round 1
// baseline (1527.961 us; speedup 1.0000x reference)
//
#include <hip/hip_runtime.h>
#include <math.h>

// SidNet signed diffusion, S/D-decoupled bf16 state.
// NEW this round: feature-chunk x XCD sharding of the gather table.
//   State is chunk-major: SD[c][row][8 x uint2]  (chunk c = features 16c..16c+15,
//   slots 0-3 = S-system, slots 4-7 = D-system, 4 bf16 per uint2).
//   Layer grid = 8 chunks x row-blocks, chunk = blockIdx & 7 -> round-robin
//   dispatch pins chunk c to XCD c. Each XCD's random-gather working set is a
//   3.2 MB slice that stays resident in its private 4 MB L2 across all layers
//   (the chunk's Out slice is written by the same XCD that reads it next layer).
//   This converts the 271 MB/layer of L2-miss gather traffic into L2 hits.
// CSR build (bucket partition) unchanged from previous round.

#define TB 256

__device__ __forceinline__ unsigned pack_bf16(float a, float b) {
    unsigned ua = __float_as_uint(a), ub = __float_as_uint(b);
    ua += 0x7fffu + ((ua >> 16) & 1u);   // RNE
    ub += 0x7fffu + ((ub >> 16) & 1u);
    return (ua >> 16) | (ub & 0xffff0000u);
}

__device__ __forceinline__ float2 unpack_bf16(unsigned w) {
    float2 r;
    r.x = __uint_as_float(w << 16);
    r.y = __uint_as_float(w & 0xffff0000u);
    return r;
}

__global__ void zero_int_kernel(int* __restrict__ p, int n) {
    int i = blockIdx.x * blockDim.x + threadIdx.x;
    if (i < n) p[i] = 0;
}

// K1: bucket histogram (bucket = row>>9), LDS-staged to keep global atomics rare.
__global__ void bucket_count_kernel(const int* __restrict__ rows_p,
                                    const int* __restrict__ rows_m,
                                    int E, int* __restrict__ bcnt) {
    __shared__ int h[128];
    for (int i = threadIdx.x; i < 128; i += TB) h[i] = 0;
    __syncthreads();
    int total = 2 * E;
    for (int e = blockIdx.x * TB + threadIdx.x; e < total; e += gridDim.x * TB) {
        int r = (e < E) ? rows_p[e] : rows_m[e - E];
        atomicAdd(&h[r >> 9], 1);
    }
    __syncthreads();
    for (int i = threadIdx.x; i < 128; i += TB)
        if (h[i]) atomicAdd(&bcnt[i], h[i]);
}

// K2: single-wave exclusive scan of 128 bucket counts -> boff[0..128], bcur copy.
__global__ void bucket_scan_kernel(const int* __restrict__ bcnt,
                                   int* __restrict__ boff, int* __restrict__ bcur) {
    int l = threadIdx.x;              // 0..63
    int v0 = bcnt[l], v1 = bcnt[l + 64];
    int i0 = v0, i1 = v1;
#pragma unroll
    for (int o = 1; o < 64; o <<= 1) { int y = __shfl_up(i0, o); if (l >= o) i0 += y; }
#pragma unroll
    for (int o = 1; o < 64; o <<= 1) { int y = __shfl_up(i1, o); if (l >= o) i1 += y; }
    int t0 = __shfl(i0, 63);          // total of low half
    int e0 = i0 - v0;
    int e1 = i1 - v1 + t0;
    boff[l] = e0;      boff[l + 64] = e1;
    bcur[l] = e0;      bcur[l + 64] = e1;
    if (l == 63) boff[128] = i1 + t0; // grand total = 2E
}

// K3: tile-local bucket sort in LDS, then coalesced run-writes to stage[].
__global__ __launch_bounds__(TB) void partition_kernel(
    const int* __restrict__ rows_p, const int* __restrict__ cols_p,
    const float* __restrict__ vals_p,
    const int* __restrict__ rows_m, const int* __restrict__ cols_m,
    const float* __restrict__ vals_m, int E,
    int* __restrict__ bcur_g, uint2* __restrict__ stage) {
    __shared__ unsigned keys[2048];
    __shared__ float    vals[2048];
    __shared__ unsigned skeys[2048];
    __shared__ float    svals[2048];
    __shared__ int h[128], boff[128], bcur[128], bbase[128];
    int tile0 = blockIdx.x * 2048;
    int cnt = min(2048, 2 * E - tile0);

    for (int i = threadIdx.x; i < cnt; i += TB) {
        int e = tile0 + i; int r, c; float v;
        if (e < E) { r = rows_p[e]; c = cols_p[e]; v = vals_p[e]; }
        else       { r = rows_m[e - E]; c = cols_m[e - E]; v = -vals_m[e - E]; }
        keys[i] = ((unsigned)r << 16) | (unsigned)c;
        vals[i] = v;
    }
    for (int i = threadIdx.x; i < 128; i += TB) { h[i] = 0; bcur[i] = 0; }
    __syncthreads();
    for (int i = threadIdx.x; i < cnt; i += TB) atomicAdd(&h[keys[i] >> 25], 1);
    __syncthreads();
    if (threadIdx.x < 64) {           // wave 0: scan 128 counters
        int l = threadIdx.x;
        int v0 = h[l], v1 = h[l + 64], i0 = v0, i1 = v1;
#pragma unroll
        for (int o = 1; o < 64; o <<= 1) { int y = __shfl_up(i0, o); if (l >= o) i0 += y; }
#pragma unroll
        for (int o = 1; o < 64; o <<= 1) { int y = __shfl_up(i1, o); if (l >= o) i1 += y; }
        int t0 = __shfl(i0, 63);
        boff[l] = i0 - v0;
        boff[l + 64] = i1 - v1 + t0;
    }
    __syncthreads();
    for (int i = threadIdx.x; i < cnt; i += TB) {
        unsigned k = keys[i]; int b = k >> 25;
        int p = boff[b] + atomicAdd(&bcur[b], 1);
        skeys[p] = k; svals[p] = vals[i];
    }
    __syncthreads();
    if (threadIdx.x < 128) {
        int c_ = h[threadIdx.x];
        if (c_) bbase[threadIdx.x] = atomicAdd(&bcur_g[threadIdx.x], c_);
    }
    __syncthreads();
    for (int i = threadIdx.x; i < cnt; i += TB) {
        unsigned k = skeys[i]; int b = k >> 25;
        stage[bbase[b] + (i - boff[b])] = make_uint2(k, __float_as_uint(svals[i]));
    }
}

// K4: one block per bucket (512 rows). LDS row-histogram + scan -> off[],
// then scatter records into the bucket's contiguous CSR range (block-owned).
__global__ __launch_bounds__(TB) void csr_finalize_kernel(
    const uint2* __restrict__ stage, const int* __restrict__ boff_g,
    int NBv, int N, int E2, int* __restrict__ off, int2* __restrict__ edge) {
    __shared__ int rc[512], ro[512], rcur[512];
    int b = blockIdx.x;
    int row0 = b << 9;
    int s0 = boff_g[b], s1 = boff_g[b + 1];
    for (int i = threadIdx.x; i < 512; i += TB) { rc[i] = 0; rcur[i] = 0; }
    __syncthreads();
    for (int i = s0 + threadIdx.x; i < s1; i += TB)
        atomicAdd(&rc[(stage[i].x >> 16) - row0], 1);
    __syncthreads();
    if (threadIdx.x < 64) {           // wave 0: exclusive scan of 512 counts
        int l = threadIdx.x;
        int s = 0, loc[8];
#pragma unroll
        for (int j = 0; j < 8; ++j) { loc[j] = s; s += rc[l * 8 + j]; }
        int incl = s;
#pragma unroll
        for (int o = 1; o < 64; o <<= 1) { int y = __shfl_up(incl, o); if (l >= o) incl += y; }
        int base = incl - s;
#pragma unroll
        for (int j = 0; j < 8; ++j) ro[l * 8 + j] = base + loc[j];
    }
    __syncthreads();
    for (int i = threadIdx.x; i < 512; i += TB) {
        int r = row0 + i;
        if (r < N) off[r] = s0 + ro[i];
    }
    if (b == NBv - 1 && threadIdx.x == 0) off[N] = E2;
    for (int i = s0 + threadIdx.x; i < s1; i += TB) {
        uint2 rec = stage[i];
        int lr = (int)(rec.x >> 16) - row0;
        int p = s0 + ro[lr] + atomicAdd(&rcur[lr], 1);
        edge[p] = make_int2((int)(rec.x & 0xffffu), (int)rec.y);
    }
}

// Init, chunk-major: thread i -> row r=i>>5, feature-quad q5=i&31.
// chunk c = q5>>2 (16 feats), within-chunk quad q = q5&3.
// SD[c][r][slot]: slot q = S-quad, slot 4+q = D-quad. tXb[c][r][q] = 0.15*X quad.
__global__ void init_kernel(const float* __restrict__ X, const float* __restrict__ M0,
                            uint2* __restrict__ SD, uint2* __restrict__ tXb,
                            int n32, int N) {
    int i = blockIdx.x * blockDim.x + threadIdx.x;
    if (i < n32) {
        int r = i >> 5, q5 = i & 31;
        int c = q5 >> 2, q = q5 & 3;
        float4 x = ((const float4*)X)[(size_t)r * 32 + q5];
        float4 m = ((const float4*)M0)[(size_t)r * 32 + q5];
        size_t rb = (size_t)c * N + r;
        SD[rb * 8 + q]     = make_uint2(pack_bf16(x.x + m.x, x.y + m.y),
                                        pack_bf16(x.z + m.z, x.w + m.w));
        SD[rb * 8 + 4 + q] = make_uint2(pack_bf16(x.x - m.x, x.y - m.y),
                                        pack_bf16(x.z - m.z, x.w - m.w));
        tXb[rb * 4 + q]    = make_uint2(pack_bf16(0.15f * x.x, 0.15f * x.y),
                                        pack_bf16(0.15f * x.z, 0.15f * x.w));
    }
}

// Layer, chunked: block -> (chunk c = blockIdx&7, rowblock = blockIdx>>3).
// 4 waves/block, each wave does 4 consecutive rows serially.
// Wave lanes = 8 edge-subgroups x 8 slots. Per step the wave covers 8 edges'
// full chunk contribution (8 edges x 16 feats x 2 systems = 256 MACs).
// slot>>2 selects system: 0 -> S uses |v| (mask 0x7fffffff), 1 -> D uses v.
// Epilogue: shfl_xor(8/16/32) reduce over edge-subgroups, add restart term,
// lanes 0-7 store the 64 B row-chunk. Last layer pairs S/D via shfl_xor(4)
// and writes fp32 P/M feature-slices directly.
__global__ __launch_bounds__(TB) void layer_kernel(
    const int* __restrict__ off, const int2* __restrict__ edge,
    const uint2* __restrict__ In, uint2* __restrict__ Out,
    const uint2* __restrict__ tXb,
    float* __restrict__ Pout, float* __restrict__ Mout, int last, int N) {
    int c = blockIdx.x & 7;
    int rowblk = blockIdx.x >> 3;
    int wid = threadIdx.x >> 6;
    int lane = threadIdx.x & 63;
    int slot = lane & 7;
    int e_sub = lane >> 3;
    int sys = slot >> 2;
    int q = slot & 3;
    unsigned vmask = sys ? 0xffffffffu : 0x7fffffffu;

    const uint2* Inc  = In  + (size_t)c * N * 8;
    uint2*       Outc = Out + (size_t)c * N * 8;
    const uint2* tXc  = tXb + (size_t)c * N * 4;

    int row0 = (rowblk << 4) + (wid << 2);
    for (int rr = 0; rr < 4; ++rr) {
        int row = row0 + rr;
        if (row >= N) return;
        int bg = off[row], en = off[row + 1];
        float a0 = 0.f, a1 = 0.f, a2 = 0.f, a3 = 0.f;

        int j = bg;
        for (; j + 16 <= en; j += 16) {      // 2 gathers in flight per wave
            int2 eA = edge[j + e_sub];
            int2 eB = edge[j + 8 + e_sub];
            uint2 wA = Inc[(size_t)eA.x * 8 + slot];
            uint2 wB = Inc[(size_t)eB.x * 8 + slot];
            float vA = __uint_as_float(((unsigned)eA.y) & vmask);
            float vB = __uint_as_float(((unsigned)eB.y) & vmask);
            float2 gA0 = unpack_bf16(wA.x), gA1 = unpack_bf16(wA.y);
            float2 gB0 = unpack_bf16(wB.x), gB1 = unpack_bf16(wB.y);
            a0 += vA * gA0.x + vB * gB0.x;
            a1 += vA * gA0.y + vB * gB0.y;
            a2 += vA * gA1.x + vB * gB1.x;
            a3 += vA * gA1.y + vB * gB1.y;
        }
        for (; j < en; j += 8) {             // masked tail, 8 edges/step
            int idx = j + e_sub;
            int2 er = make_int2(0, 0);
            if (idx < en) er = edge[idx];
            uint2 w = Inc[(size_t)er.x * 8 + slot];
            float v = __uint_as_float(((unsigned)er.y) & vmask);
            float2 g0 = unpack_bf16(w.x), g1 = unpack_bf16(w.y);
            a0 += v * g0.x; a1 += v * g0.y; a2 += v * g1.x; a3 += v * g1.y;
        }

        // reduce over the 8 edge-subgroups (lane bits 3..5)
        a0 += __shfl_xor(a0, 8); a0 += __shfl_xor(a0, 16); a0 += __shfl_xor(a0, 32);
        a1 += __shfl_xor(a1, 8); a1 += __shfl_xor(a1, 16); a1 += __shfl_xor(a1, 32);
        a2 += __shfl_xor(a2, 8); a2 += __shfl_xor(a2, 16); a2 += __shfl_xor(a2, 32);
        a3 += __shfl_xor(a3, 8); a3 += __shfl_xor(a3, 16); a3 += __shfl_xor(a3, 32);

        // restart term (same for S and D systems)
        uint2 t = tXc[(size_t)row * 4 + q];
        float2 t0 = unpack_bf16(t.x), t1 = unpack_bf16(t.y);
        a0 += t0.x; a1 += t0.y; a2 += t1.x; a3 += t1.y;

        if (!last) {
            if (lane < 8)
                Outc[(size_t)row * 8 + slot] =
                    make_uint2(pack_bf16(a0, a1), pack_bf16(a2, a3));
        } else {
            // pair S/D: slot^4 holds the other system, same feature quad
            float b0 = __shfl_xor(a0, 4), b1 = __shfl_xor(a1, 4);
            float b2 = __shfl_xor(a2, 4), b3 = __shfl_xor(a3, 4);
            if (lane < 8) {
                if (sys == 0) {   // P = (S+D)/2
                    ((float4*)Pout)[(size_t)row * 32 + 4 * c + q] =
                        make_float4(0.5f * (a0 + b0), 0.5f * (a1 + b1),
                                    0.5f * (a2 + b2), 0.5f * (a3 + b3));
                } else {          // M = (S-D)/2, here a=D, b=S
                    ((float4*)Mout)[(size_t)row * 32 + 4 * c + q] =
                        make_float4(0.5f * (b0 - a0), 0.5f * (b1 - a1),
                                    0.5f * (b2 - a2), 0.5f * (b3 - a3));
                }
            }
        }
    }
}

extern "C" void kernel_launch(void* const* d_in, const int* in_sizes, int n_in,
                              void* d_out, int out_size, void* d_ws, size_t ws_size,
                              hipStream_t stream) {
    const int*   rows_p = (const int*)d_in[0];
    const int*   cols_p = (const int*)d_in[1];
    const float* vals_p = (const float*)d_in[2];
    const int*   rows_m = (const int*)d_in[3];
    const int*   cols_m = (const int*)d_in[4];
    const float* vals_m = (const float*)d_in[5];
    const float* X      = (const float*)d_in[6];
    const float* M0     = (const float*)d_in[7];

    const int E = in_sizes[0];
    const int D = 128;
    const int N = in_sizes[6] / D;       // 50000 (<65536: 16-bit r/c packing ok)
    const int K = 10;
    const int E2 = 2 * E;
    const size_t ND = (size_t)N * D;
    const int N32 = N * 32;
    const int NBv = (N + 511) >> 9;      // buckets of 512 rows, <=128

    float* outP = (float*)d_out;
    float* outM = outP + ND;

    char* ws = (char*)d_ws;
    size_t o = 0;
    auto alloc = [&](size_t b) -> void* {
        void* p = ws + o;
        o += (b + 255) & ~(size_t)255;
        return p;
    };
    uint2* SDA  = (uint2*)alloc((size_t)N * 64 * 8);
    uint2* SDB  = (uint2*)alloc((size_t)N * 64 * 8);
    uint2* tXb  = (uint2*)alloc((size_t)N * 32 * 8);
    int*   off  = (int*)alloc((size_t)(N + 1) * sizeof(int));
    int2*  edge = (int2*)alloc((size_t)E2 * sizeof(int2));
    int*   bcnt = (int*)alloc(128 * sizeof(int));
    int*   boff = (int*)alloc(129 * sizeof(int));
    int*   bcur = (int*)alloc(128 * sizeof(int));
    // stage aliases SDB: consumed by csr_finalize before layer 0 writes SDB.
    uint2* stage = SDB;

    int gN32 = (N32 + TB - 1) / TB;
    int gTiles = (E2 + 2047) / 2048;

    // --- CSR build: bucket partition with LDS write-combining ---
    zero_int_kernel<<<1, 128, 0, stream>>>(bcnt, 128);
    bucket_count_kernel<<<512, TB, 0, stream>>>(rows_p, rows_m, E, bcnt);
    bucket_scan_kernel<<<1, 64, 0, stream>>>(bcnt, boff, bcur);
    partition_kernel<<<gTiles, TB, 0, stream>>>(rows_p, cols_p, vals_p,
                                                rows_m, cols_m, vals_m, E,
                                                bcur, stage);
    csr_finalize_kernel<<<NBv, TB, 0, stream>>>(stage, boff, NBv, N, E2, off, edge);

    // --- init chunk-major bf16 state ---
    init_kernel<<<gN32, TB, 0, stream>>>(X, M0, SDA, tXb, N32, N);

    // --- K layers, ping-pong; chunk = blockIdx&7 pins chunk to XCD ---
    int nRB = (N + 15) >> 4;             // 16 rows per block (4 waves x 4 rows)
    int gL = nRB * 8;
    uint2 *Si = SDA, *So = SDB;
    for (int k = 0; k < K; ++k) {
        int last = (k == K - 1);
        layer_kernel<<<gL, TB, 0, stream>>>(off, edge, Si, So, tXb,
                                            outP, outM, last, N);
        uint2* t = Si; Si = So; So = t;
    }
}